// Round 1
// baseline (428.198 us; speedup 1.0000x reference)
//
#include <hip/hip_runtime.h>
#include <math.h>

#define B_ 16
#define S_ 512
#define DM 1024
#define NH 16
#define DFF 2048

typedef short bf16x8 __attribute__((ext_vector_type(8)));
typedef float f32x4 __attribute__((ext_vector_type(4)));
typedef unsigned short u16;

__device__ __forceinline__ u16 f2bf(float f) {
  unsigned int u = __float_as_uint(f);
  u += 0x7FFF + ((u >> 16) & 1);
  return (u16)(u >> 16);
}

__device__ __forceinline__ float gelu_exact(float x) {
  return 0.5f * x * (1.0f + erff(x * 0.70710678118654752f));
}

__device__ __forceinline__ void gload_lds16(const void* g, void* l) {
  __builtin_amdgcn_global_load_lds((const __attribute__((address_space(1))) void*)g,
                                   (__attribute__((address_space(3))) void*)l, 16, 0, 0);
}

// ---------------------------------------------------------------- small utils

__global__ void cvt_bf16_k(const float* __restrict__ in, u16* __restrict__ out, int n) {
  int i = (blockIdx.x * blockDim.x + threadIdx.x) * 4;
  float4 v = *(const float4*)(in + i);
  uint2 pk;
  pk.x = (unsigned)f2bf(v.x) | ((unsigned)f2bf(v.y) << 16);
  pk.y = (unsigned)f2bf(v.z) | ((unsigned)f2bf(v.w) << 16);
  *(uint2*)(out + i) = pk;
}

// W[K][N] fp32 -> Wt[N][K] bf16
__global__ void transpose_bf16(const float* __restrict__ W, u16* __restrict__ Wt, int K, int N) {
  __shared__ float tile[32][33];
  int n0 = blockIdx.x * 32, k0 = blockIdx.y * 32;
  int tx = threadIdx.x, ty = threadIdx.y;
#pragma unroll
  for (int j = 0; j < 32; j += 8)
    tile[ty + j][tx] = W[(size_t)(k0 + ty + j) * N + n0 + tx];
  __syncthreads();
#pragma unroll
  for (int j = 0; j < 32; j += 8)
    Wt[(size_t)(n0 + ty + j) * K + k0 + tx] = f2bf(tile[tx][ty + j]);
}

__global__ void bias_cat(const float* __restrict__ bq, const float* __restrict__ bk,
                         const float* __restrict__ bv, float* __restrict__ o) {
  int i = blockIdx.x * 256 + threadIdx.x;  // 3072 total
  o[i] = (i < 1024) ? bq[i] : ((i < 2048) ? bk[i - 1024] : bv[i - 2048]);
}

// ---------------------------------------------------------------- GEMM (bf16 MFMA)
// C[M][N] = A[M][K] @ Bt[N][K]^T + bias.  128x128 tile, BK=32, 4 waves.
// EPI: 1 = GELU -> bf16 out (ldc=N); 2 = fp32 out (ldc=N);
//      3 = QKV mode: col<2048 -> bf16 qk buffer (ldc=2048), col>=2048 -> vT scatter.
template <int EPI>
__global__ __launch_bounds__(256, 2)
void gemm_bt(const u16* __restrict__ A, const u16* __restrict__ Bt,
             const float* __restrict__ bias, void* __restrict__ Cout,
             u16* __restrict__ vT, int M, int N, int K) {
  __shared__ __align__(16) char lds[16384];  // A tile [128][32] bf16 @0, B tile @8192
  const int tid = threadIdx.x;
  const int w = tid >> 6, lane = tid & 63;
  const int bn = blockIdx.x, bm = blockIdx.y;
  const int wm = w >> 1, wn = w & 1;
  const int l4 = lane >> 2;          // row within 16-row chunk
  const int lk = (lane & 3) * 8;     // element offset in K

  char* ldsA = lds;
  char* ldsB = lds + 8192;

  const int c0 = w * 2 + 0, c1 = w * 2 + 1;
  const u16* a0 = A + (size_t)(bm * 128 + c0 * 16 + l4) * K + lk;
  const u16* a1 = A + (size_t)(bm * 128 + c1 * 16 + l4) * K + lk;
  const u16* b0 = Bt + (size_t)(bn * 128 + c0 * 16 + l4) * K + lk;
  const u16* b1 = Bt + (size_t)(bn * 128 + c1 * 16 + l4) * K + lk;
  char* da0 = ldsA + c0 * 1024;
  char* da1 = ldsA + c1 * 1024;
  char* db0 = ldsB + c0 * 1024;
  char* db1 = ldsB + c1 * 1024;

  f32x4 acc[4][4];
#pragma unroll
  for (int i = 0; i < 4; ++i)
#pragma unroll
    for (int j = 0; j < 4; ++j) acc[i][j] = (f32x4){0.f, 0.f, 0.f, 0.f};

  const int arow = lane & 15;
  const int kb = (lane >> 4) * 16;  // byte offset of this lane's 8 bf16 in K

  for (int k0 = 0; k0 < K; k0 += 32) {
    gload_lds16(a0, da0);
    gload_lds16(a1, da1);
    gload_lds16(b0, db0);
    gload_lds16(b1, db1);
    a0 += 32; a1 += 32; b0 += 32; b1 += 32;
    __syncthreads();

    bf16x8 af[4], bfv[4];
#pragma unroll
    for (int mi = 0; mi < 4; ++mi)
      af[mi] = *(const bf16x8*)(ldsA + (wm * 64 + mi * 16 + arow) * 64 + kb);
#pragma unroll
    for (int ni = 0; ni < 4; ++ni)
      bfv[ni] = *(const bf16x8*)(ldsB + (wn * 64 + ni * 16 + arow) * 64 + kb);
#pragma unroll
    for (int mi = 0; mi < 4; ++mi)
#pragma unroll
      for (int ni = 0; ni < 4; ++ni)
        acc[mi][ni] = __builtin_amdgcn_mfma_f32_16x16x32_bf16(af[mi], bfv[ni], acc[mi][ni], 0, 0, 0);
    __syncthreads();
  }

  const int crow0 = bm * 128 + wm * 64;
  const int ccol0 = bn * 128 + wn * 64;
#pragma unroll
  for (int mi = 0; mi < 4; ++mi) {
#pragma unroll
    for (int ni = 0; ni < 4; ++ni) {
      const int col = ccol0 + ni * 16 + (lane & 15);
      const float bv = bias[col];
#pragma unroll
      for (int r = 0; r < 4; ++r) {
        const int row = crow0 + mi * 16 + (lane >> 4) * 4 + r;
        float v = acc[mi][ni][r] + bv;
        if (EPI == 1) {
          v = gelu_exact(v);
          ((u16*)Cout)[(size_t)row * N + col] = f2bf(v);
        } else if (EPI == 2) {
          ((float*)Cout)[(size_t)row * N + col] = v;
        } else {  // EPI == 3
          if (col < 2048) {
            ((u16*)Cout)[(size_t)row * 2048 + col] = f2bf(v);
          } else {
            const int b = row >> 9, s = row & 511;
            const int hd = col - 2048;
            vT[((size_t)(b * NH + (hd >> 6)) * 64 + (hd & 63)) * S_ + s] = f2bf(v);
          }
        }
      }
    }
  }
}

// ---------------------------------------------------------------- attention
// block = (qt, h, b): 32 q-rows of one head. 256 threads / 4 waves.
__global__ __launch_bounds__(256, 2)
void attn_kernel(const u16* __restrict__ qk,   // [8192][2048]: q cols 0..1023, k cols 1024..2047
                 const u16* __restrict__ vT,   // [B][H][64][512]
                 const int* __restrict__ mask, // [B][512]
                 u16* __restrict__ out) {      // [8192][1024]
  __shared__ __align__(16) float Sc[32 * 516];
  __shared__ __align__(16) u16 Qs[32 * 72];
  __shared__ int Ml[512];
  const int tid = threadIdx.x;
  const int w = tid >> 6, lane = tid & 63;
  const int qt = blockIdx.x, h = blockIdx.y, b = blockIdx.z;
  const int q0 = qt * 32;
  const int arow = lane & 15, kg = lane >> 4;

  {  // stage Q tile [32][64] -> rows padded to 144B
    int r = tid >> 3, slot = tid & 7;
    bf16x8 v = *(const bf16x8*)(qk + (size_t)(b * S_ + q0 + r) * 2048 + h * 64 + slot * 8);
    *(bf16x8*)((char*)Qs + r * 144 + slot * 16) = v;
  }
  Ml[tid] = mask[b * S_ + tid];
  Ml[tid + 256] = mask[b * S_ + tid + 256];
  __syncthreads();

  {  // QK^T -> Sc (masked, scaled)
    bf16x8 af[2][2];
#pragma unroll
    for (int mi = 0; mi < 2; ++mi)
#pragma unroll
      for (int kk = 0; kk < 2; ++kk)
        af[mi][kk] = *(const bf16x8*)((char*)Qs + (mi * 16 + arow) * 144 + kk * 64 + kg * 16);
    const u16* kbase = qk + (size_t)(b * S_) * 2048 + 1024 + h * 64;
#pragma unroll
    for (int ni = 0; ni < 8; ++ni) {
      const int colg = w * 128 + ni * 16 + arow;
      const u16* kr = kbase + (size_t)colg * 2048 + kg * 8;
      bf16x8 bk0 = *(const bf16x8*)(kr);
      bf16x8 bk1 = *(const bf16x8*)(kr + 32);
      f32x4 s0 = {0.f, 0.f, 0.f, 0.f}, s1 = {0.f, 0.f, 0.f, 0.f};
      s0 = __builtin_amdgcn_mfma_f32_16x16x32_bf16(af[0][0], bk0, s0, 0, 0, 0);
      s0 = __builtin_amdgcn_mfma_f32_16x16x32_bf16(af[0][1], bk1, s0, 0, 0, 0);
      s1 = __builtin_amdgcn_mfma_f32_16x16x32_bf16(af[1][0], bk0, s1, 0, 0, 0);
      s1 = __builtin_amdgcn_mfma_f32_16x16x32_bf16(af[1][1], bk1, s1, 0, 0, 0);
      const bool msk = (Ml[colg] == 0);
#pragma unroll
      for (int r = 0; r < 4; ++r) {
        const int rr = kg * 4 + r;
        Sc[rr * 516 + colg] = msk ? -1e10f : s0[r] * 0.125f;
        Sc[(16 + rr) * 516 + colg] = msk ? -1e10f : s1[r] * 0.125f;
      }
    }
  }
  __syncthreads();

  {  // softmax in place; thread t: row=t>>3, 64-col segment s=t&7
    const int r = tid >> 3, s = tid & 7;
    float* base = Sc + r * 516 + s * 64;
    float m = -3.0e38f;
#pragma unroll
    for (int j = 0; j < 16; ++j) {
      f32x4 v = *(const f32x4*)(base + j * 4);
      m = fmaxf(m, fmaxf(fmaxf(v[0], v[1]), fmaxf(v[2], v[3])));
    }
    m = fmaxf(m, __shfl_xor(m, 1));
    m = fmaxf(m, __shfl_xor(m, 2));
    m = fmaxf(m, __shfl_xor(m, 4));
    float sum = 0.f;
#pragma unroll
    for (int j = 0; j < 16; ++j) {
      f32x4 v = *(const f32x4*)(base + j * 4);
#pragma unroll
      for (int e = 0; e < 4; ++e) v[e] = __expf(v[e] - m);
      sum += v[0] + v[1] + v[2] + v[3];
      *(f32x4*)(base + j * 4) = v;
    }
    sum += __shfl_xor(sum, 1);
    sum += __shfl_xor(sum, 2);
    sum += __shfl_xor(sum, 4);
    const float inv = 1.0f / sum;
#pragma unroll
    for (int j = 0; j < 16; ++j) {
      f32x4 v = *(const f32x4*)(base + j * 4);
#pragma unroll
      for (int e = 0; e < 4; ++e) v[e] *= inv;
      *(f32x4*)(base + j * 4) = v;
    }
  }
  __syncthreads();

  {  // PV: wave w owns dk columns w*16..w*16+15
    f32x4 oa[2];
    oa[0] = (f32x4){0.f, 0.f, 0.f, 0.f};
    oa[1] = (f32x4){0.f, 0.f, 0.f, 0.f};
    const u16* vb = vT + ((size_t)(b * NH + h) * 64 + w * 16 + arow) * S_ + kg * 8;
#pragma unroll
    for (int t16 = 0; t16 < 16; ++t16) {
      const int sk0 = t16 * 32;
      bf16x8 bfr = *(const bf16x8*)(vb + sk0);
#pragma unroll
      for (int mi = 0; mi < 2; ++mi) {
        const float* ps = Sc + (mi * 16 + arow) * 516 + sk0 + kg * 8;
        f32x4 p0 = *(const f32x4*)(ps);
        f32x4 p1 = *(const f32x4*)(ps + 4);
        bf16x8 pa;
        pa[0] = (short)f2bf(p0[0]); pa[1] = (short)f2bf(p0[1]);
        pa[2] = (short)f2bf(p0[2]); pa[3] = (short)f2bf(p0[3]);
        pa[4] = (short)f2bf(p1[0]); pa[5] = (short)f2bf(p1[1]);
        pa[6] = (short)f2bf(p1[2]); pa[7] = (short)f2bf(p1[3]);
        oa[mi] = __builtin_amdgcn_mfma_f32_16x16x32_bf16(pa, bfr, oa[mi], 0, 0, 0);
      }
    }
#pragma unroll
    for (int mi = 0; mi < 2; ++mi)
#pragma unroll
      for (int r = 0; r < 4; ++r) {
        const int qrow = q0 + mi * 16 + kg * 4 + r;
        out[(size_t)(b * S_ + qrow) * DM + h * 64 + w * 16 + arow] = f2bf(oa[mi][r]);
      }
  }
}

// ---------------------------------------------------------------- residual + LayerNorm
// out = gamma*(v-mean)/(std+eps)+beta, v = a+res; unbiased var (N-1), eps on std.
__global__ __launch_bounds__(256)
void ln_kernel(const float* __restrict__ a, const float* __restrict__ res,
               const float* __restrict__ gamma, const float* __restrict__ beta,
               float* __restrict__ out, u16* __restrict__ outb) {
  const int row = blockIdx.x, tid = threadIdx.x;
  const int w = tid >> 6, lane = tid & 63;
  const size_t base = (size_t)row * DM + tid * 4;
  float4 va = *(const float4*)(a + base);
  float4 vr = *(const float4*)(res + base);
  float v0 = va.x + vr.x, v1 = va.y + vr.y, v2 = va.z + vr.z, v3 = va.w + vr.w;
  float s = v0 + v1 + v2 + v3;
  float ss = v0 * v0 + v1 * v1 + v2 * v2 + v3 * v3;
#pragma unroll
  for (int off = 32; off >= 1; off >>= 1) {
    s += __shfl_down(s, off);
    ss += __shfl_down(ss, off);
  }
  __shared__ float ps[4], pss[4], mb[2];
  if (lane == 0) { ps[w] = s; pss[w] = ss; }
  __syncthreads();
  if (tid == 0) {
    float S = ps[0] + ps[1] + ps[2] + ps[3];
    float SS = pss[0] + pss[1] + pss[2] + pss[3];
    float mean = S * (1.0f / DM);
    float var = (SS - (float)DM * mean * mean) * (1.0f / (DM - 1));
    var = fmaxf(var, 0.f);
    mb[0] = mean;
    mb[1] = 1.0f / (sqrtf(var) + 1e-6f);
  }
  __syncthreads();
  const float mean = mb[0], rinv = mb[1];
  const int c = tid * 4;
  float y0 = gamma[c] * (v0 - mean) * rinv + beta[c];
  float y1 = gamma[c + 1] * (v1 - mean) * rinv + beta[c + 1];
  float y2 = gamma[c + 2] * (v2 - mean) * rinv + beta[c + 2];
  float y3 = gamma[c + 3] * (v3 - mean) * rinv + beta[c + 3];
  float4 o = {y0, y1, y2, y3};
  *(float4*)(out + base) = o;
  if (outb) {
    uint2 pk;
    pk.x = (unsigned)f2bf(y0) | ((unsigned)f2bf(y1) << 16);
    pk.y = (unsigned)f2bf(y2) | ((unsigned)f2bf(y3) << 16);
    *(uint2*)(outb + base) = pk;
  }
}

// ---------------------------------------------------------------- launch

extern "C" void kernel_launch(void* const* d_in, const int* in_sizes, int n_in,
                              void* d_out, int out_size, void* d_ws, size_t ws_size,
                              hipStream_t stream) {
  const float* x = (const float*)d_in[0];
  const int* xm = (const int*)d_in[1];
  const float* Wq = (const float*)d_in[2];
  const float* bq = (const float*)d_in[3];
  const float* Wk = (const float*)d_in[4];
  const float* bk = (const float*)d_in[5];
  const float* Wv = (const float*)d_in[6];
  const float* bv = (const float*)d_in[7];
  const float* Wo = (const float*)d_in[8];
  const float* bo = (const float*)d_in[9];
  const float* g1 = (const float*)d_in[10];
  const float* be1 = (const float*)d_in[11];
  const float* W1 = (const float*)d_in[12];
  const float* b1 = (const float*)d_in[13];
  const float* W2 = (const float*)d_in[14];
  const float* b2 = (const float*)d_in[15];
  const float* g2 = (const float*)d_in[16];
  const float* be2 = (const float*)d_in[17];

  char* ws = (char*)d_ws;
  u16* xb = (u16*)(ws);                      // 16,777,216 (reused as h_bf16)
  u16* wqkvt = (u16*)(ws + 16777216);        //  6,291,456
  u16* wot = (u16*)(ws + 23068672);          //  2,097,152
  u16* w1t = (u16*)(ws + 25165824);          //  4,194,304
  u16* w2t = (u16*)(ws + 29360128);          //  4,194,304
  float* bqkv = (float*)(ws + 33554432);     //     12,288
  u16* qkb = (u16*)(ws + 33566720);          // 33,554,432 (reused as ffn1)
  u16* vtb = (u16*)(ws + 67121152);          // 16,777,216
  u16* attnb = (u16*)(ws + 83898368);        // 16,777,216
  float* f32a = (float*)(ws + 100675584);    // 33,554,432 (attn_proj, then ffn2)
  float* hbuf = (float*)(ws + 134230016);    // 33,554,432 ; end ~168MB
  u16* hb = xb;

  cvt_bf16_k<<<dim3(8192), dim3(256), 0, stream>>>(x, xb, 8388608);
  transpose_bf16<<<dim3(32, 32), dim3(32, 8), 0, stream>>>(Wq, wqkvt, 1024, 1024);
  transpose_bf16<<<dim3(32, 32), dim3(32, 8), 0, stream>>>(Wk, wqkvt + 1024 * 1024, 1024, 1024);
  transpose_bf16<<<dim3(32, 32), dim3(32, 8), 0, stream>>>(Wv, wqkvt + 2 * 1024 * 1024, 1024, 1024);
  transpose_bf16<<<dim3(32, 32), dim3(32, 8), 0, stream>>>(Wo, wot, 1024, 1024);
  transpose_bf16<<<dim3(64, 32), dim3(32, 8), 0, stream>>>(W1, w1t, 1024, 2048);
  transpose_bf16<<<dim3(32, 64), dim3(32, 8), 0, stream>>>(W2, w2t, 2048, 1024);
  bias_cat<<<dim3(12), dim3(256), 0, stream>>>(bq, bk, bv, bqkv);

  // QKV: [8192,1024] @ [1024,3072] -> qk (q,k) + vT scatter
  gemm_bt<3><<<dim3(24, 64), dim3(256), 0, stream>>>(xb, wqkvt, bqkv, (void*)qkb, vtb, 8192, 3072, 1024);
  attn_kernel<<<dim3(16, 16, 16), dim3(256), 0, stream>>>(qkb, vtb, xm, attnb);
  // attn @ Wo -> fp32
  gemm_bt<2><<<dim3(8, 64), dim3(256), 0, stream>>>(attnb, wot, bo, (void*)f32a, (u16*)nullptr, 8192, 1024, 1024);
  ln_kernel<<<dim3(8192), dim3(256), 0, stream>>>(f32a, x, g1, be1, hbuf, hb);
  // FFN1 + GELU -> bf16 (reuse qkb)
  gemm_bt<1><<<dim3(16, 64), dim3(256), 0, stream>>>(hb, w1t, b1, (void*)qkb, (u16*)nullptr, 8192, 2048, 1024);
  // FFN2 -> fp32 (reuse f32a)
  gemm_bt<2><<<dim3(8, 64), dim3(256), 0, stream>>>(qkb, w2t, b2, (void*)f32a, (u16*)nullptr, 8192, 1024, 2048);
  ln_kernel<<<dim3(8192), dim3(256), 0, stream>>>(f32a, hbuf, g2, be2, (float*)d_out, (u16*)nullptr);
}

// Round 2
// 366.247 us; speedup vs baseline: 1.1692x; 1.1692x over previous
//
#include <hip/hip_runtime.h>
#include <math.h>

#define B_ 16
#define S_ 512
#define DM 1024
#define NH 16
#define DFF 2048

typedef short bf16x8 __attribute__((ext_vector_type(8)));
typedef float f32x4 __attribute__((ext_vector_type(4)));
typedef unsigned short u16;

__device__ __forceinline__ u16 f2bf(float f) {
  unsigned int u = __float_as_uint(f);
  u += 0x7FFF + ((u >> 16) & 1);
  return (u16)(u >> 16);
}

__device__ __forceinline__ float gelu_exact(float x) {
  return 0.5f * x * (1.0f + erff(x * 0.70710678118654752f));
}

__device__ __forceinline__ void gload_lds16(const void* g, void* l) {
  __builtin_amdgcn_global_load_lds((const __attribute__((address_space(1))) void*)g,
                                   (__attribute__((address_space(3))) void*)l, 16, 0, 0);
}

// ---------------------------------------------------------------- small utils

__global__ void cvt_bf16_k(const float* __restrict__ in, u16* __restrict__ out, int n) {
  int i = (blockIdx.x * blockDim.x + threadIdx.x) * 4;
  float4 v = *(const float4*)(in + i);
  uint2 pk;
  pk.x = (unsigned)f2bf(v.x) | ((unsigned)f2bf(v.y) << 16);
  pk.y = (unsigned)f2bf(v.z) | ((unsigned)f2bf(v.w) << 16);
  *(uint2*)(out + i) = pk;
}

// W[K][N] fp32 -> Wt[N][K] bf16
__global__ void transpose_bf16(const float* __restrict__ W, u16* __restrict__ Wt, int K, int N) {
  __shared__ float tile[32][33];
  int n0 = blockIdx.x * 32, k0 = blockIdx.y * 32;
  int tx = threadIdx.x, ty = threadIdx.y;
#pragma unroll
  for (int j = 0; j < 32; j += 8)
    tile[ty + j][tx] = W[(size_t)(k0 + ty + j) * N + n0 + tx];
  __syncthreads();
#pragma unroll
  for (int j = 0; j < 32; j += 8)
    Wt[(size_t)(n0 + ty + j) * K + k0 + tx] = f2bf(tile[tx][ty + j]);
}

__global__ void bias_cat(const float* __restrict__ bq, const float* __restrict__ bk,
                         const float* __restrict__ bv, float* __restrict__ o) {
  int i = blockIdx.x * 256 + threadIdx.x;  // 3072 total
  o[i] = (i < 1024) ? bq[i] : ((i < 2048) ? bk[i - 1024] : bv[i - 2048]);
}

// ---------------------------------------------------------------- GEMM (bf16 MFMA)
// C[M][N] = A[M][K] @ Bt[N][K]^T + bias.  128x128 tile, BK=32, 4 waves.
// EPI: 1 = GELU -> bf16 out (ldc=N); 2 = fp32 out (ldc=N);
//      3 = QKV mode: col<2048 -> bf16 qk buffer (ldc=2048), col>=2048 -> vT scatter.
template <int EPI>
__global__ __launch_bounds__(256, 2)
void gemm_bt(const u16* __restrict__ A, const u16* __restrict__ Bt,
             const float* __restrict__ bias, void* __restrict__ Cout,
             u16* __restrict__ vT, int M, int N, int K) {
  __shared__ __align__(16) char lds[16384];  // A tile [128][32] bf16 @0, B tile @8192
  const int tid = threadIdx.x;
  const int w = tid >> 6, lane = tid & 63;
  const int bn = blockIdx.x, bm = blockIdx.y;
  const int wm = w >> 1, wn = w & 1;
  const int l4 = lane >> 2;          // row within 16-row chunk
  const int lk = (lane & 3) * 8;     // element offset in K

  char* ldsA = lds;
  char* ldsB = lds + 8192;

  const int c0 = w * 2 + 0, c1 = w * 2 + 1;
  const u16* a0 = A + (size_t)(bm * 128 + c0 * 16 + l4) * K + lk;
  const u16* a1 = A + (size_t)(bm * 128 + c1 * 16 + l4) * K + lk;
  const u16* b0 = Bt + (size_t)(bn * 128 + c0 * 16 + l4) * K + lk;
  const u16* b1 = Bt + (size_t)(bn * 128 + c1 * 16 + l4) * K + lk;
  char* da0 = ldsA + c0 * 1024;
  char* da1 = ldsA + c1 * 1024;
  char* db0 = ldsB + c0 * 1024;
  char* db1 = ldsB + c1 * 1024;

  f32x4 acc[4][4];
#pragma unroll
  for (int i = 0; i < 4; ++i)
#pragma unroll
    for (int j = 0; j < 4; ++j) acc[i][j] = (f32x4){0.f, 0.f, 0.f, 0.f};

  const int arow = lane & 15;
  const int kb = (lane >> 4) * 16;  // byte offset of this lane's 8 bf16 in K

  for (int k0 = 0; k0 < K; k0 += 32) {
    gload_lds16(a0, da0);
    gload_lds16(a1, da1);
    gload_lds16(b0, db0);
    gload_lds16(b1, db1);
    a0 += 32; a1 += 32; b0 += 32; b1 += 32;
    __syncthreads();

    bf16x8 af[4], bfv[4];
#pragma unroll
    for (int mi = 0; mi < 4; ++mi)
      af[mi] = *(const bf16x8*)(ldsA + (wm * 64 + mi * 16 + arow) * 64 + kb);
#pragma unroll
    for (int ni = 0; ni < 4; ++ni)
      bfv[ni] = *(const bf16x8*)(ldsB + (wn * 64 + ni * 16 + arow) * 64 + kb);
#pragma unroll
    for (int mi = 0; mi < 4; ++mi)
#pragma unroll
      for (int ni = 0; ni < 4; ++ni)
        acc[mi][ni] = __builtin_amdgcn_mfma_f32_16x16x32_bf16(af[mi], bfv[ni], acc[mi][ni], 0, 0, 0);
    __syncthreads();
  }

  const int crow0 = bm * 128 + wm * 64;
  const int ccol0 = bn * 128 + wn * 64;
#pragma unroll
  for (int mi = 0; mi < 4; ++mi) {
#pragma unroll
    for (int ni = 0; ni < 4; ++ni) {
      const int col = ccol0 + ni * 16 + (lane & 15);
      const float bv = bias[col];
#pragma unroll
      for (int r = 0; r < 4; ++r) {
        const int row = crow0 + mi * 16 + (lane >> 4) * 4 + r;
        float v = acc[mi][ni][r] + bv;
        if (EPI == 1) {
          v = gelu_exact(v);
          ((u16*)Cout)[(size_t)row * N + col] = f2bf(v);
        } else if (EPI == 2) {
          ((float*)Cout)[(size_t)row * N + col] = v;
        } else {  // EPI == 3
          if (col < 2048) {
            ((u16*)Cout)[(size_t)row * 2048 + col] = f2bf(v);
          } else {
            const int b = row >> 9, s = row & 511;
            const int hd = col - 2048;
            vT[((size_t)(b * NH + (hd >> 6)) * 64 + (hd & 63)) * S_ + s] = f2bf(v);
          }
        }
      }
    }
  }
}

// ---------------------------------------------------------------- attention
// block = one (qt,h,b) tile: 32 q-rows of one head. 256 threads / 4 waves.
// Register-resident softmax: QK^T accumulators stay in VGPRs, row max/sum via
// shfl_xor(1,2,4,8) within 16-lane col groups + [32][4] LDS cross-wave reduce.
// P written once, unnormalized bf16, [32][520] (row stride 1040B => banks
// rotate by 4/row, balanced groups). 1/sum applied at PV epilogue.
__global__ __launch_bounds__(256, 3)
void attn_kernel(const u16* __restrict__ qk,   // [8192][2048]: q cols 0..1023, k cols 1024..2047
                 const u16* __restrict__ vT,   // [B][H][64][512]
                 const int* __restrict__ mask, // [B][512]
                 u16* __restrict__ out) {      // [8192][1024]
  __shared__ __align__(16) u16 Qs[32 * 72];
  __shared__ __align__(16) u16 Pl[32 * 520];
  __shared__ int Ml[512];
  __shared__ __align__(16) float Rmax[32][4];
  __shared__ __align__(16) float Rsum[32][4];

  const int tid = threadIdx.x;
  const int w = tid >> 6, lane = tid & 63;
  // XCD-aware swizzle: bid%8 ~ XCD; give each XCD a contiguous chunk of work
  // so the 16 q-tiles sharing a head's K/V panel stay L2-local.
  const int bid = blockIdx.x;
  const int widx = (bid & 7) * 512 + (bid >> 3);
  const int qt = widx & 15, h = (widx >> 4) & 15, b = widx >> 8;
  const int q0 = qt * 32;
  const int arow = lane & 15, kg = lane >> 4;

  {  // stage Q tile [32][64] -> rows padded to 144B
    int r = tid >> 3, slot = tid & 7;
    bf16x8 v = *(const bf16x8*)(qk + (size_t)(b * S_ + q0 + r) * 2048 + h * 64 + slot * 8);
    *(bf16x8*)((char*)Qs + r * 144 + slot * 16) = v;
  }
  Ml[tid] = mask[b * S_ + tid];
  Ml[tid + 256] = mask[b * S_ + tid + 256];
  __syncthreads();

  // ---- QK^T into registers. Lane (arow,kg) of wave w holds, for q-rows
  // kg*4+r (s0) and 16+kg*4+r (s1), k-cols w*128 + ni*16 + arow.
  f32x4 s0[8], s1[8];
  {
    bf16x8 af[2][2];
#pragma unroll
    for (int mi = 0; mi < 2; ++mi)
#pragma unroll
      for (int kk = 0; kk < 2; ++kk)
        af[mi][kk] = *(const bf16x8*)((char*)Qs + (mi * 16 + arow) * 144 + kk * 64 + kg * 16);
    const u16* kbase = qk + (size_t)(b * S_) * 2048 + 1024 + h * 64;
#pragma unroll
    for (int ni = 0; ni < 8; ++ni) {
      const int colg = w * 128 + ni * 16 + arow;
      const u16* kr = kbase + (size_t)colg * 2048 + kg * 8;
      bf16x8 bk0 = *(const bf16x8*)(kr);
      bf16x8 bk1 = *(const bf16x8*)(kr + 32);
      f32x4 a0 = {0.f, 0.f, 0.f, 0.f}, a1 = {0.f, 0.f, 0.f, 0.f};
      a0 = __builtin_amdgcn_mfma_f32_16x16x32_bf16(af[0][0], bk0, a0, 0, 0, 0);
      a0 = __builtin_amdgcn_mfma_f32_16x16x32_bf16(af[0][1], bk1, a0, 0, 0, 0);
      a1 = __builtin_amdgcn_mfma_f32_16x16x32_bf16(af[1][0], bk0, a1, 0, 0, 0);
      a1 = __builtin_amdgcn_mfma_f32_16x16x32_bf16(af[1][1], bk1, a1, 0, 0, 0);
      const bool msk = (Ml[colg] == 0);
#pragma unroll
      for (int r = 0; r < 4; ++r) {
        s0[ni][r] = msk ? -1e10f : a0[r] * 0.125f;
        s1[ni][r] = msk ? -1e10f : a1[r] * 0.125f;
      }
    }
  }

  // ---- row max: in-lane over ni, shfl over the 16 arow lanes, LDS over waves
  float m0[4], m1[4];
#pragma unroll
  for (int r = 0; r < 4; ++r) {
    float a = fmaxf(fmaxf(s0[0][r], s0[1][r]), fmaxf(s0[2][r], s0[3][r]));
    float c = fmaxf(fmaxf(s0[4][r], s0[5][r]), fmaxf(s0[6][r], s0[7][r]));
    m0[r] = fmaxf(a, c);
    a = fmaxf(fmaxf(s1[0][r], s1[1][r]), fmaxf(s1[2][r], s1[3][r]));
    c = fmaxf(fmaxf(s1[4][r], s1[5][r]), fmaxf(s1[6][r], s1[7][r]));
    m1[r] = fmaxf(a, c);
  }
#pragma unroll
  for (int d = 1; d < 16; d <<= 1) {
#pragma unroll
    for (int r = 0; r < 4; ++r) {
      m0[r] = fmaxf(m0[r], __shfl_xor(m0[r], d));
      m1[r] = fmaxf(m1[r], __shfl_xor(m1[r], d));
    }
  }
  if (arow == 0) {
#pragma unroll
    for (int r = 0; r < 4; ++r) {
      Rmax[kg * 4 + r][w] = m0[r];
      Rmax[16 + kg * 4 + r][w] = m1[r];
    }
  }
  __syncthreads();
  float fm0[4], fm1[4];
#pragma unroll
  for (int r = 0; r < 4; ++r) {
    f32x4 v = *(const f32x4*)&Rmax[kg * 4 + r][0];
    fm0[r] = fmaxf(fmaxf(v[0], v[1]), fmaxf(v[2], v[3]));
    v = *(const f32x4*)&Rmax[16 + kg * 4 + r][0];
    fm1[r] = fmaxf(fmaxf(v[0], v[1]), fmaxf(v[2], v[3]));
  }

  // ---- exp in registers + partial row sums; write unnormalized bf16 P
  float t0[4] = {0.f, 0.f, 0.f, 0.f}, t1[4] = {0.f, 0.f, 0.f, 0.f};
#pragma unroll
  for (int ni = 0; ni < 8; ++ni) {
#pragma unroll
    for (int r = 0; r < 4; ++r) {
      s0[ni][r] = __expf(s0[ni][r] - fm0[r]);
      t0[r] += s0[ni][r];
      s1[ni][r] = __expf(s1[ni][r] - fm1[r]);
      t1[r] += s1[ni][r];
    }
  }
#pragma unroll
  for (int ni = 0; ni < 8; ++ni) {
    const int colg = w * 128 + ni * 16 + arow;
#pragma unroll
    for (int r = 0; r < 4; ++r) {
      Pl[(kg * 4 + r) * 520 + colg] = f2bf(s0[ni][r]);
      Pl[(16 + kg * 4 + r) * 520 + colg] = f2bf(s1[ni][r]);
    }
  }
#pragma unroll
  for (int d = 1; d < 16; d <<= 1) {
#pragma unroll
    for (int r = 0; r < 4; ++r) {
      t0[r] += __shfl_xor(t0[r], d);
      t1[r] += __shfl_xor(t1[r], d);
    }
  }
  if (arow == 0) {
#pragma unroll
    for (int r = 0; r < 4; ++r) {
      Rsum[kg * 4 + r][w] = t0[r];
      Rsum[16 + kg * 4 + r][w] = t1[r];
    }
  }
  __syncthreads();  // covers P writes + Rsum

  // ---- PV: wave w owns dk columns w*16..w*16+15
  {
    f32x4 oa[2];
    oa[0] = (f32x4){0.f, 0.f, 0.f, 0.f};
    oa[1] = (f32x4){0.f, 0.f, 0.f, 0.f};
    const u16* vb = vT + ((size_t)(b * NH + h) * 64 + w * 16 + arow) * S_ + kg * 8;
#pragma unroll
    for (int t16 = 0; t16 < 16; ++t16) {
      const int sk0 = t16 * 32;
      bf16x8 bfr = *(const bf16x8*)(vb + sk0);
#pragma unroll
      for (int mi = 0; mi < 2; ++mi) {
        bf16x8 pa = *(const bf16x8*)(Pl + (mi * 16 + arow) * 520 + sk0 + kg * 8);
        oa[mi] = __builtin_amdgcn_mfma_f32_16x16x32_bf16(pa, bfr, oa[mi], 0, 0, 0);
      }
    }
#pragma unroll
    for (int mi = 0; mi < 2; ++mi)
#pragma unroll
      for (int r = 0; r < 4; ++r) {
        const int rloc = mi * 16 + kg * 4 + r;
        f32x4 sv = *(const f32x4*)&Rsum[rloc][0];
        const float inv = 1.0f / (sv[0] + sv[1] + sv[2] + sv[3]);
        const int qrow = q0 + rloc;
        out[(size_t)(b * S_ + qrow) * DM + h * 64 + w * 16 + arow] = f2bf(oa[mi][r] * inv);
      }
  }
}

// ---------------------------------------------------------------- residual + LayerNorm
// out = gamma*(v-mean)/(std+eps)+beta, v = a+res; unbiased var (N-1), eps on std.
__global__ __launch_bounds__(256)
void ln_kernel(const float* __restrict__ a, const float* __restrict__ res,
               const float* __restrict__ gamma, const float* __restrict__ beta,
               float* __restrict__ out, u16* __restrict__ outb) {
  const int row = blockIdx.x, tid = threadIdx.x;
  const int w = tid >> 6, lane = tid & 63;
  const size_t base = (size_t)row * DM + tid * 4;
  float4 va = *(const float4*)(a + base);
  float4 vr = *(const float4*)(res + base);
  float v0 = va.x + vr.x, v1 = va.y + vr.y, v2 = va.z + vr.z, v3 = va.w + vr.w;
  float s = v0 + v1 + v2 + v3;
  float ss = v0 * v0 + v1 * v1 + v2 * v2 + v3 * v3;
#pragma unroll
  for (int off = 32; off >= 1; off >>= 1) {
    s += __shfl_down(s, off);
    ss += __shfl_down(ss, off);
  }
  __shared__ float ps[4], pss[4], mb[2];
  if (lane == 0) { ps[w] = s; pss[w] = ss; }
  __syncthreads();
  if (tid == 0) {
    float S = ps[0] + ps[1] + ps[2] + ps[3];
    float SS = pss[0] + pss[1] + pss[2] + pss[3];
    float mean = S * (1.0f / DM);
    float var = (SS - (float)DM * mean * mean) * (1.0f / (DM - 1));
    var = fmaxf(var, 0.f);
    mb[0] = mean;
    mb[1] = 1.0f / (sqrtf(var) + 1e-6f);
  }
  __syncthreads();
  const float mean = mb[0], rinv = mb[1];
  const int c = tid * 4;
  float y0 = gamma[c] * (v0 - mean) * rinv + beta[c];
  float y1 = gamma[c + 1] * (v1 - mean) * rinv + beta[c + 1];
  float y2 = gamma[c + 2] * (v2 - mean) * rinv + beta[c + 2];
  float y3 = gamma[c + 3] * (v3 - mean) * rinv + beta[c + 3];
  float4 o = {y0, y1, y2, y3};
  *(float4*)(out + base) = o;
  if (outb) {
    uint2 pk;
    pk.x = (unsigned)f2bf(y0) | ((unsigned)f2bf(y1) << 16);
    pk.y = (unsigned)f2bf(y2) | ((unsigned)f2bf(y3) << 16);
    *(uint2*)(outb + base) = pk;
  }
}

// ---------------------------------------------------------------- launch

extern "C" void kernel_launch(void* const* d_in, const int* in_sizes, int n_in,
                              void* d_out, int out_size, void* d_ws, size_t ws_size,
                              hipStream_t stream) {
  const float* x = (const float*)d_in[0];
  const int* xm = (const int*)d_in[1];
  const float* Wq = (const float*)d_in[2];
  const float* bq = (const float*)d_in[3];
  const float* Wk = (const float*)d_in[4];
  const float* bk = (const float*)d_in[5];
  const float* Wv = (const float*)d_in[6];
  const float* bv = (const float*)d_in[7];
  const float* Wo = (const float*)d_in[8];
  const float* bo = (const float*)d_in[9];
  const float* g1 = (const float*)d_in[10];
  const float* be1 = (const float*)d_in[11];
  const float* W1 = (const float*)d_in[12];
  const float* b1 = (const float*)d_in[13];
  const float* W2 = (const float*)d_in[14];
  const float* b2 = (const float*)d_in[15];
  const float* g2 = (const float*)d_in[16];
  const float* be2 = (const float*)d_in[17];

  char* ws = (char*)d_ws;
  u16* xb = (u16*)(ws);                      // 16,777,216 (reused as h_bf16)
  u16* wqkvt = (u16*)(ws + 16777216);        //  6,291,456
  u16* wot = (u16*)(ws + 23068672);          //  2,097,152
  u16* w1t = (u16*)(ws + 25165824);          //  4,194,304
  u16* w2t = (u16*)(ws + 29360128);          //  4,194,304
  float* bqkv = (float*)(ws + 33554432);     //     12,288
  u16* qkb = (u16*)(ws + 33566720);          // 33,554,432 (reused as ffn1)
  u16* vtb = (u16*)(ws + 67121152);          // 16,777,216
  u16* attnb = (u16*)(ws + 83898368);        // 16,777,216
  float* f32a = (float*)(ws + 100675584);    // 33,554,432 (attn_proj, then ffn2)
  float* hbuf = (float*)(ws + 134230016);    // 33,554,432 ; end ~168MB
  u16* hb = xb;

  cvt_bf16_k<<<dim3(8192), dim3(256), 0, stream>>>(x, xb, 8388608);
  transpose_bf16<<<dim3(32, 32), dim3(32, 8), 0, stream>>>(Wq, wqkvt, 1024, 1024);
  transpose_bf16<<<dim3(32, 32), dim3(32, 8), 0, stream>>>(Wk, wqkvt + 1024 * 1024, 1024, 1024);
  transpose_bf16<<<dim3(32, 32), dim3(32, 8), 0, stream>>>(Wv, wqkvt + 2 * 1024 * 1024, 1024, 1024);
  transpose_bf16<<<dim3(32, 32), dim3(32, 8), 0, stream>>>(Wo, wot, 1024, 1024);
  transpose_bf16<<<dim3(64, 32), dim3(32, 8), 0, stream>>>(W1, w1t, 1024, 2048);
  transpose_bf16<<<dim3(32, 64), dim3(32, 8), 0, stream>>>(W2, w2t, 2048, 1024);
  bias_cat<<<dim3(12), dim3(256), 0, stream>>>(bq, bk, bv, bqkv);

  // QKV: [8192,1024] @ [1024,3072] -> qk (q,k) + vT scatter
  gemm_bt<3><<<dim3(24, 64), dim3(256), 0, stream>>>(xb, wqkvt, bqkv, (void*)qkb, vtb, 8192, 3072, 1024);
  attn_kernel<<<dim3(4096), dim3(256), 0, stream>>>(qkb, vtb, xm, attnb);
  // attn @ Wo -> fp32
  gemm_bt<2><<<dim3(8, 64), dim3(256), 0, stream>>>(attnb, wot, bo, (void*)f32a, (u16*)nullptr, 8192, 1024, 1024);
  ln_kernel<<<dim3(8192), dim3(256), 0, stream>>>(f32a, x, g1, be1, hbuf, hb);
  // FFN1 + GELU -> bf16 (reuse qkb)
  gemm_bt<1><<<dim3(16, 64), dim3(256), 0, stream>>>(hb, w1t, b1, (void*)qkb, (u16*)nullptr, 8192, 2048, 1024);
  // FFN2 -> fp32 (reuse f32a)
  gemm_bt<2><<<dim3(8, 64), dim3(256), 0, stream>>>(qkb, w2t, b2, (void*)f32a, (u16*)nullptr, 8192, 1024, 2048);
  ln_kernel<<<dim3(8192), dim3(256), 0, stream>>>(f32a, hbuf, g2, be2, (float*)d_out, (u16*)nullptr);
}